// Round 11
// baseline (665.586 us; speedup 1.0000x reference)
//
#include <hip/hip_runtime.h>
#include <stdint.h>

typedef unsigned short u16;
typedef __bf16 bf16x8 __attribute__((ext_vector_type(8)));
typedef float f32x4 __attribute__((ext_vector_type(4)));

// Geometry
// x: [8, 512, 100, 100] NCHW (dtype runtime-detected: f32 or bf16). Padded grid 102x102.
// xt: channels-last padded input [b][row][c] bf16, row = 128-guard + p, per-batch stride 10752 rows.
// feat: [b][p][o] bf16, per-batch stride 10496 rows.
// wA: [o][cchunk*576 + s*64 + c_in]  (K-order: c-chunk major, shift s, 64 c_in)
#define XT_STRIDE 10752
#define XT_GUARD  128
#define NPAD      10496
#define NT        82

__device__ __forceinline__ float b2f(u16 u) {
  union { unsigned int i; float f; } v; v.i = ((unsigned int)u) << 16; return v.f;
}
__device__ __forceinline__ u16 f2b(float f) {
  union { float f; unsigned int i; } v; v.f = f;
  unsigned int u = v.i;
  unsigned int r = u + 0x7FFFu + ((u >> 16) & 1u);  // RNE, finite inputs
  return (u16)(r >> 16);
}
__device__ __forceinline__ float ldin(const void* p, long i, int f32) {
  return f32 ? ((const float*)p)[i] : b2f(((const u16*)p)[i]);
}
// async global->LDS, 16B per lane; LDS dest = wave-uniform base + lane*16
__device__ __forceinline__ void async16(const void* g, void* l) {
  __builtin_amdgcn_global_load_lds(
      (const __attribute__((address_space(1))) unsigned int*)g,
      (__attribute__((address_space(3))) unsigned int*)l, 16, 0, 0);
}
// Wave-level dtype sniff (64 lanes scan a 16KB window of x).
__device__ __forceinline__ int sniff_is_f32(const void* x) {
  const uint4* p = (const uint4*)x;
  const int lane = threadIdx.x & 63;
  unsigned int acc = 0;
  #pragma unroll
  for (int i = 0; i < 16; ++i) {
    uint4 v = p[i * 64 + lane];
    unsigned int w0 = v.x, w1 = v.y, w2 = v.z, w3 = v.w;
    acc |= ((w0 & 0x7F80u) == 0x7F80u) | (((w0 >> 16) & 0x7F80u) == 0x7F80u);
    acc |= ((w1 & 0x7F80u) == 0x7F80u) | (((w1 >> 16) & 0x7F80u) == 0x7F80u);
    acc |= ((w2 & 0x7F80u) == 0x7F80u) | (((w2 >> 16) & 0x7F80u) == 0x7F80u);
    acc |= ((w3 & 0x7F80u) == 0x7F80u) | (((w3 >> 16) & 0x7F80u) == 0x7F80u);
  }
  return __any(acc != 0) ? 1 : 0;
}

// ---------------- k_sniff: one-wave dtype detection, publishes flag for all later kernels --------
__global__ __launch_bounds__(64) void k_sniff(const void* __restrict__ x, int* __restrict__ flagOut) {
  const int f32 = sniff_is_f32(x);
  if (threadIdx.x == 0) *flagOut = f32;
}

// ---------------- k_prep: fused zero-pads + transpose + wA-shuffle + wH/bias pack ----------------
// Roles by block range (independent, disjoint writes):
//   [0,6400): transpose  (b 8 x h 100 x cb 8)
//   [6400,7904): zero xt pad/guard cells (8 x 188)
//   [7904,8928): wA shuffle (1024)
//   [8928,9024): wH + biases (96)
// dtype flag comes from k_sniff (launched before on the same stream).
// UNCHANGED from R10 — this round's k_conv split puts k_prep into the rocprof top-5 for the
// first time; keep it byte-identical so the measurement attributes cleanly.
__global__ __launch_bounds__(256) void k_prep(const void* __restrict__ x,
                                              const void* __restrict__ w_rpn,
                                              const void* __restrict__ b_rpn,
                                              const void* __restrict__ w_cls,
                                              const void* __restrict__ b_cls,
                                              const void* __restrict__ w_bbox,
                                              const void* __restrict__ b_bbox,
                                              u16* __restrict__ xt,
                                              u16* __restrict__ wA,
                                              u16* __restrict__ wH,
                                              float* __restrict__ bAll,
                                              const int* __restrict__ flag) {
  const int blk = blockIdx.x;
  const int t = threadIdx.x;
  if (blk < 6400) {
    // ---- transpose: unit = 8 channels x 4 w; reg transpose, 16B stores ----
    const int f32 = *flag;
    if (t >= 200) return;
    const int b = blk / 800, r = blk - b * 800;
    const int h = r >> 3, cb = r & 7;
    const int co = t & 7, jw = t >> 3;
    const int c0 = cb * 64 + co * 8;
    u16 v[8][4];
    if (!f32) {
      const u16* src = (const u16*)x + (long)(b * 512 + c0) * 10000 + h * 100 + jw * 4;
      #pragma unroll
      for (int dc = 0; dc < 8; ++dc) {
        uint2 u = *(const uint2*)(src + (long)dc * 10000);
        const u16* pv = (const u16*)&u;
        v[dc][0] = pv[0]; v[dc][1] = pv[1]; v[dc][2] = pv[2]; v[dc][3] = pv[3];
      }
    } else {
      const float* src = (const float*)x + (long)(b * 512 + c0) * 10000 + h * 100 + jw * 4;
      #pragma unroll
      for (int dc = 0; dc < 8; ++dc) {
        float4 u = *(const float4*)(src + (long)dc * 10000);
        v[dc][0] = f2b(u.x); v[dc][1] = f2b(u.y); v[dc][2] = f2b(u.z); v[dc][3] = f2b(u.w);
      }
    }
    u16* dst = xt + ((long)b * XT_STRIDE + XT_GUARD + (h + 1) * 102 + 1 + jw * 4) * 512 + c0;
    #pragma unroll
    for (int dw = 0; dw < 4; ++dw) {
      union { uint4 u; u16 s[8]; } pk;
      #pragma unroll
      for (int dc = 0; dc < 8; ++dc) pk.s[dc] = v[dc][dw];
      *(uint4*)(dst + (long)dw * 512) = pk.u;
    }
  } else if (blk < 7904) {
    // ---- zero pad/guard cells of xt (48128 uint4 units per batch) ----
    const int i2 = blk - 6400;
    const int b = i2 / 188, bx = i2 - b * 188;
    const int i = bx * 256 + t;
    if (i >= 48128) return;
    int row, sub;
    if (i < 35328) {
      int rr = i >> 6; sub = i & 63;
      row = (rr < 230) ? rr : (10200 + rr);  // [0,230) or [10430,10752)
    } else {
      int j = i - 35328;
      int ci = j >> 6; sub = j & 63;
      int pr = (ci >> 1) + 1;
      row = XT_GUARD + pr * 102 + (ci & 1) * 101;
    }
    uint4 z = {0, 0, 0, 0};
    *(uint4*)(xt + ((long)b * XT_STRIDE + row) * 512 + sub * 8) = z;
  } else if (blk < 8928) {
    // ---- wA: [o][c][3][3] -> [o][cchunk*576 + s*64 + c_in]  (s-fastest K order) ----
    const int f32 = *flag;
    const int idx = (blk - 7904) * 256 + t;     // o*512+c
    const int o = idx >> 9, c = idx & 511;
    u16* dst = wA + (long)o * 4608 + (c >> 6) * 576 + (c & 63);
    #pragma unroll
    for (int s = 0; s < 9; ++s) dst[s * 64] = f2b(ldin(w_rpn, (long)idx * 9 + s, f32));
  } else {
    // ---- wH [48][512] (45 real + 3 zero rows) + biases ----
    const int f32 = *flag;
    const int idx = (blk - 8928) * 256 + t;     // < 24576
    const int a = idx >> 9, c = idx & 511;
    float v = 0.f;
    if (a < 9) v = ldin(w_cls, a * 512 + c, f32);
    else if (a < 45) v = ldin(w_bbox, (a - 9) * 512 + c, f32);
    wH[idx] = f2b(v);
    if (idx < 512) bAll[idx] = ldin(b_rpn, idx, f32);
    if (c == 0) {
      float bv = 0.f;
      if (a < 9) bv = ldin(b_cls, a, f32);
      else if (a < 45) bv = ldin(b_bbox, a - 9, f32);
      bAll[512 + a] = bv;
    }
  }
}

// ---------------- Conv implicit GEMM: 128x128 tile, BK=64, B-BAND reuse (R10, 336us @58% util) ----
// SPLIT into two half-grid dispatches this round (blk0 = 0 / 1312 -> batches 0-3 / 4-7) so
// k_prep/k_head finally enter the rocprof top-5 with counters. Each half is a complete
// independent GEMM (feat writes disjoint); 1312%8==0 preserves the XCD swizzle pattern.
// Kernel body is byte-identical to R10 apart from the blk0 offset.
__global__ __launch_bounds__(256, 4) void k_conv(const u16* __restrict__ xt, const u16* __restrict__ wA,
                                                 const float* __restrict__ bAll, u16* __restrict__ feat,
                                                 const int blk0) {
  __shared__ u16 sA[128 * 64];   // 16 KB
  __shared__ u16 sB[132 * 64];   // 16.9 KB band (130 used + 2 pad rows)
  __shared__ float sBias[128];
  const int t = threadIdx.x;
  const int i = blockIdx.x + blk0;     // 0..2623 across the two launches
  const int xcd = i & 7, j = i >> 3;   // j: 0..327
  const int mtb = j / 82, nt = j - mtb * 82;
  const int pair = xcd + 8 * mtb;      // 0..31
  const int mt = pair & 3, b = pair >> 2;
  const int m0 = mt * 128, n0 = nt * 128;
  if (t < 128) sBias[t] = bAll[m0 + t];
  f32x4 acc[4][4] = {};
  const int lane = t & 63, wv = t >> 6;
  const int srow = t >> 3;                              // staging row 0..31 (+32 per round)
  const int sseg = (((t & 7) ^ (srow & 7))) * 8;        // XOR-permuted source segment
  const int mh = (wv & 1) * 64, nh = (wv >> 1) * 64;
  const int l15 = lane & 15, q = lane >> 4;
  const int s7 = l15 & 7;                               // A reader XOR key (row&7)
  u16* sAw = sA + wv * 512;                             // wave staging base (1KB/wave)
  const u16* gA = wA + (long)(m0 + srow) * 4608 + sseg;
  const u16* xtb = xt + ((long)b * XT_STRIDE + XT_GUARD) * 512;
  const u16* rowA = sA + (mh + l15) * 64;               // A frag row base
  for (int ks = 0; ks < 72; ++ks) {
    const int k0 = ks * 64;
    const int cchunk = ks / 9;
    const int s = ks - cchunk * 9;                      // shift 0..8, FASTEST
    const int dh = s / 3, dw = s - dh * 3;
    const int c0 = cchunk * 64;
    // A stage: every step (72 distinct K-slices)
    async16(gA + k0, sAw);
    async16(gA + k0 + (long)32 * 4608, sAw + 32 * 64);
    async16(gA + k0 + (long)64 * 4608, sAw + 64 * 64);
    async16(gA + k0 + (long)96 * 4608, sAw + 96 * 64);
    // B band stage: once per dh (dw==0); reused by dw=0,1,2. 130 rows x 64 c.
    if (dw == 0) {
      const long bs = (long)n0 + (dh - 1) * 102 - 1;    // band start row (rel. to guard base)
      const u16* gBb = xtb + (bs + srow) * 512 + c0 + sseg;
      #pragma unroll
      for (int k = 0; k < 4; ++k)                        // rows 32k + srow
        async16(gBb + (long)k * 32 * 512, sB + (k * 32 + wv * 8) * 64);
      if (t < 16)                                        // partial: rows 128,129 (wave 0 lanes)
        async16(gBb + (long)128 * 512, sB + 128 * 64);
    }
    asm volatile("s_waitcnt vmcnt(0)" ::: "memory");    // drain async-LDS before barrier
    __syncthreads();
    const int s7b = (l15 + dw) & 7;                     // B reader XOR key (band row &7)
    const u16* rowB = sB + (nh + dw + l15) * 64;        // band-local row = nh+ni*16+l15+dw
    #pragma unroll
    for (int h = 0; h < 2; ++h) {
      const int segA = ((h * 4 + q) ^ s7) * 8;          // un-swizzle: seg idx h*4+q
      const int segB = ((h * 4 + q) ^ s7b) * 8;
      bf16x8 af[4], bf[4];
      #pragma unroll
      for (int mi = 0; mi < 4; ++mi) af[mi] = *(const bf16x8*)(rowA + mi * 1024 + segA);
      #pragma unroll
      for (int ni = 0; ni < 4; ++ni) bf[ni] = *(const bf16x8*)(rowB + ni * 1024 + segB);
      #pragma unroll
      for (int mi = 0; mi < 4; ++mi)
        #pragma unroll
        for (int ni = 0; ni < 4; ++ni)
          acc[mi][ni] = __builtin_amdgcn_mfma_f32_16x16x32_bf16(af[mi], bf[ni], acc[mi][ni], 0, 0, 0);
    }
    __syncthreads();                                    // band/A safe to restage next step
  }
  u16* fb = feat + (long)b * NPAD * 512;
  #pragma unroll
  for (int mi = 0; mi < 4; ++mi) {
    const int ol = mh + mi * 16 + q * 4;
    #pragma unroll
    for (int ni = 0; ni < 4; ++ni) {
      const int p = n0 + nh + ni * 16 + l15;
      unsigned long long pk = 0;
      #pragma unroll
      for (int r = 0; r < 4; ++r) {
        float v = acc[mi][ni][r] + sBias[ol + r];
        v = v > 0.f ? v : 0.f;
        pk |= ((unsigned long long)f2b(v)) << (16 * r);
      }
      *(unsigned long long*)(fb + (long)p * 512 + m0 + ol) = pk;
    }
  }
}

// ---------------- k_head: LDS-free MFMA, dual-dtype store (flag from ws) ----------------
__global__ __launch_bounds__(256) void k_head(const u16* __restrict__ feat, const u16* __restrict__ wH,
                                              const float* __restrict__ bAll, void* __restrict__ out,
                                              const int* __restrict__ flag) {
  const int f32 = *flag;
  const int t = threadIdx.x;
  const int lane = t & 63, wv = t >> 6;
  const int l15 = lane & 15, q = lane >> 4;
  const int slot = blockIdx.x * 64 + wv * 16;          // 64 p-slots per block; NPAD%64==0
  const int b = slot / NPAD, p0 = slot - b * NPAD;
  const u16* fp = feat + ((long)b * NPAD + p0 + l15) * 512 + q * 8;
  const u16* ap = wH + (long)l15 * 512 + q * 8;
  f32x4 acc[3] = {};
  #pragma unroll
  for (int ks = 0; ks < 16; ++ks) {
    const int k0 = ks * 32;
    bf16x8 bf = *(const bf16x8*)(fp + k0);
    bf16x8 a0 = *(const bf16x8*)(ap + k0);
    bf16x8 a1 = *(const bf16x8*)(ap + 16 * 512 + k0);
    bf16x8 a2 = *(const bf16x8*)(ap + 32 * 512 + k0);
    acc[0] = __builtin_amdgcn_mfma_f32_16x16x32_bf16(a0, bf, acc[0], 0, 0, 0);
    acc[1] = __builtin_amdgcn_mfma_f32_16x16x32_bf16(a1, bf, acc[1], 0, 0, 0);
    acc[2] = __builtin_amdgcn_mfma_f32_16x16x32_bf16(a2, bf, acc[2], 0, 0, 0);
  }
  const int p = p0 + l15;
  const int pr = p / 102, pc = p - pr * 102;
  if (pr < 1 || pr > 100 || pc < 1 || pc > 100) return;  // pad position
  const int h = pr - 1, w = pc - 1;
  #pragma unroll
  for (int mi = 0; mi < 3; ++mi) {
    #pragma unroll
    for (int r = 0; r < 4; ++r) {
      const int a = mi * 16 + q * 4 + r;
      if (a >= 45) continue;
      float v = acc[mi][r] + bAll[512 + a];
      long oidx;
      if (a < 9) oidx = ((long)(b * 9 + a)) * 10000 + h * 100 + w;
      else       oidx = 720000 + ((long)(b * 36 + (a - 9))) * 10000 + h * 100 + w;
      if (f32) ((float*)out)[oidx] = v;
      else     ((u16*)out)[oidx] = f2b(v);
    }
  }
}

extern "C" void kernel_launch(void* const* d_in, const int* in_sizes, int n_in,
                              void* d_out, int out_size, void* d_ws, size_t ws_size,
                              hipStream_t stream) {
  const void* x      = d_in[0];
  const void* w_rpn  = d_in[1];
  const void* b_rpn  = d_in[2];
  const void* w_cls  = d_in[3];
  const void* b_cls  = d_in[4];
  const void* w_bbox = d_in[5];
  const void* b_bbox = d_in[6];
  char* ws = (char*)d_ws;
  u16*  xt   = (u16*) (ws);                 // 8*10752*512*2 = 88,080,384
  u16*  feat = (u16*) (ws + 88080384);      // 8*10496*512*2 = 85,983,232
  u16*  wA   = (u16*) (ws + 174063616);     // 512*4608*2    =  4,718,592
  u16*  wH   = (u16*) (ws + 178782208);     // 48*512*2      =     49,152
  float* bAll= (float*)(ws + 178831360);    // 560*4
  int*  flag = (int*) (ws + 178833600);     // 4

  k_sniff<<<1, 64, 0, stream>>>(x, flag);
  k_prep<<<9024, 256, 0, stream>>>(x, w_rpn, b_rpn, w_cls, b_cls, w_bbox, b_bbox,
                                   xt, wA, wH, bAll, flag);
  k_conv<<<1312, 256, 0, stream>>>(xt, wA, bAll, feat, 0);     // batches 0-3
  k_conv<<<1312, 256, 0, stream>>>(xt, wA, bAll, feat, 1312);  // batches 4-7
  k_head<<<1312, 256, 0, stream>>>(feat, wH, bAll, d_out, flag);
}